// Round 16
// baseline (290.753 us; speedup 1.0000x reference)
//
#include <hip/hip_runtime.h>
#include <math.h>

#define D 128
#define PROJ_EPS 1e-5f
#define MAX_NN (1.0f - PROJ_EPS)
#define MIN_NORM 1e-15f
#define ROWS_PER_BLOCK 2048

struct __align__(8) Edge { int c; float v; };

typedef __attribute__((ext_vector_type(8))) short bf16x8;
typedef __attribute__((ext_vector_type(4))) float f32x4;

// packed f32->bf16 RNE convert: dst.lo = bf16(a), dst.hi = bf16(b)
__device__ inline unsigned cvt_pk_bf16(float a, float b) {
    unsigned r;
    asm("v_cvt_pk_bf16_f32 %0, %1, %2" : "=v"(r) : "v"(a), "v"(b));
    return r;
}

__device__ inline float wave_sum(float v) {
#pragma unroll
    for (int off = 32; off; off >>= 1) v += __shfl_xor(v, off, 64);
    return v;
}
// 16-lane-group reductions
__device__ inline float g16sum(float v) {
#pragma unroll
    for (int off = 8; off; off >>= 1) v += __shfl_xor(v, off, 64);
    return v;
}
__device__ inline void g16sum2(float& a, float& b) {
#pragma unroll
    for (int off = 8; off; off >>= 1) {
        a += __shfl_xor(a, off, 64);
        b += __shfl_xor(b, off, 64);
    }
}
__device__ inline float frcp(float x) { return __builtin_amdgcn_rcpf(x); }
__device__ inline float fsqrt_(float x) { return __builtin_amdgcn_sqrtf(x); }
__device__ inline float tanh_pos(float x) {
    float e = __expf(-2.f * x);
    return (1.f - e) * frcp(1.f + e);
}
__device__ inline float tanh_sgn(float x) {
    float ax = fabsf(x);
    float e = __expf(-2.f * ax);
    float r = (1.f - e) * frcp(1.f + e);
    return copysignf(r, x);
}
__device__ inline float atanh_clip(float x) {
    return 0.5f * __logf((1.f + x) * frcp(1.f - x));
}

// ---- packed-f32 pair ops ----
__device__ inline float2 mk2(float a, float b) { float2 r; r.x = a; r.y = b; return r; }
__device__ inline float2 bc2(float a) { return mk2(a, a); }
__device__ inline float2 pk_fma2(float2 a, float2 b, float2 c) {
    float2 d;
    asm("v_pk_fma_f32 %0, %1, %2, %3" : "=v"(d) : "v"(a), "v"(b), "v"(c));
    return d;
}
__device__ inline float2 pk_mul2(float2 a, float2 b) {
    float2 d;
    asm("v_pk_mul_f32 %0, %1, %2" : "=v"(d) : "v"(a), "v"(b));
    return d;
}
__device__ inline float2 up2(unsigned u) {
    uint2 t; t.x = u << 16; t.y = u & 0xffff0000u;
    float2 r; r.x = __uint_as_float(t.x); r.y = __uint_as_float(t.y);
    return r;
}

// ---------------- CSR build ----------------
__global__ void hist_kernel(const int* __restrict__ rows, int* __restrict__ counts, int e) {
    int i = blockIdx.x * blockDim.x + threadIdx.x;
    if (i < e) atomicAdd(&counts[rows[i]], 1);
}

__global__ __launch_bounds__(256) void partial_kernel(const int* __restrict__ counts,
                                                      int* __restrict__ partials, int n) {
    int t = threadIdx.x;
    int start = blockIdx.x * ROWS_PER_BLOCK + t * 8;
    int s = 0;
#pragma unroll
    for (int j = 0; j < 8; ++j) {
        int i = start + j;
        if (i < n) s += (counts[i] + 3) & ~3;
    }
    int lane = t & 63, wv = t >> 6;
#pragma unroll
    for (int o = 32; o; o >>= 1) s += __shfl_xor(s, o, 64);
    __shared__ int wsum[4];
    if (lane == 0) wsum[wv] = s;
    __syncthreads();
    if (t == 0) partials[blockIdx.x] = wsum[0] + wsum[1] + wsum[2] + wsum[3];
}

__global__ void scan_partials(int* __restrict__ partials, int npart) {
    __shared__ int buf[1024];
    int t = threadIdx.x;
    int v = (t < npart) ? partials[t] : 0;
    buf[t] = v;
    __syncthreads();
    for (int o = 1; o < 1024; o <<= 1) {
        int x = (t >= o) ? buf[t - o] : 0;
        __syncthreads();
        buf[t] += x;
        __syncthreads();
    }
    if (t < npart) partials[t] = buf[t] - v;
}

__global__ __launch_bounds__(256) void rowptr_kernel(const int* __restrict__ counts,
                                                     const int* __restrict__ partials,
                                                     int* __restrict__ row_ptr,
                                                     int* __restrict__ cursor, int n) {
    int t = threadIdx.x;
    int start = blockIdx.x * ROWS_PER_BLOCK + t * 8;
    int c[8];
    int s = 0;
#pragma unroll
    for (int j = 0; j < 8; ++j) {
        int i = start + j;
        c[j] = (i < n) ? ((counts[i] + 3) & ~3) : 0;
        s += c[j];
    }
    int lane = t & 63, wv = t >> 6;
    int inc = s;
#pragma unroll
    for (int o = 1; o < 64; o <<= 1) {
        int tt = __shfl_up(inc, o, 64);
        if (lane >= o) inc += tt;
    }
    __shared__ int wsum[4];
    if (lane == 63) wsum[wv] = inc;
    __syncthreads();
    if (t == 0) {
        int acc = 0;
        for (int w = 0; w < 4; ++w) { int tmp = wsum[w]; wsum[w] = acc; acc += tmp; }
    }
    __syncthreads();
    int run = partials[blockIdx.x] + wsum[wv] + (inc - s);
#pragma unroll
    for (int j = 0; j < 8; ++j) {
        int i = start + j;
        if (i < n) {
            row_ptr[i] = run;
            cursor[i] = run;
            run += c[j];
            if (i == n - 1) row_ptr[n] = run;
        }
    }
}

__global__ void scatter_kernel(const int* __restrict__ rows, const int* __restrict__ cols,
                               const float* __restrict__ vals, int* __restrict__ cursor,
                               Edge* __restrict__ eds, int e) {
    int i = blockIdx.x * blockDim.x + threadIdx.x;
    if (i < e) {
        int r = rows[i];
        int pos = atomicAdd(&cursor[r], 1);
        Edge ed; ed.c = cols[i]; ed.v = vals[i];
        eds[pos] = ed;
    }
}

// ---------------- init: x = proj(ent), logscale, xnorm2 (4 rows/wave) ----------------
__global__ __launch_bounds__(256) void proj_init(const float* __restrict__ ent,
                                                 float* __restrict__ x,
                                                 float* __restrict__ logscale,
                                                 float* __restrict__ xnorm2, int n) {
    int wv = (int)((blockIdx.x * (size_t)blockDim.x + threadIdx.x) >> 6);
    int lane = threadIdx.x & 63;
    int q = lane >> 4, li = lane & 15;
    if (wv * 4 >= n) return;
    int r = wv * 4 + q;
    bool active = (r < n);
    float4 va = active ? *(const float4*)(ent + (size_t)r * D + 8 * li)
                       : make_float4(0.f, 0.f, 0.f, 0.f);
    float4 vb = active ? *(const float4*)(ent + (size_t)r * D + 8 * li + 4)
                       : make_float4(0.f, 0.f, 0.f, 0.f);
    float ss = va.x * va.x + va.y * va.y + va.z * va.z + va.w * va.w
             + vb.x * vb.x + vb.y * vb.y + vb.z * vb.z + vb.w * vb.w;
    ss = g16sum(ss);
    float nrm = fsqrt_(ss);
    float scale = (nrm > MAX_NN) ? MAX_NN * frcp(fmaxf(nrm, MIN_NORM)) : 1.0f;
    float n2 = fminf(nrm, MAX_NN);  // == ||x*scale|| analytically
    float nc = fminf(fmaxf(n2, MIN_NORM), MAX_NN);
    float ls = atanh_clip(nc) * frcp(fmaxf(n2, MIN_NORM));
    if (active) {
        *(float4*)(x + (size_t)r * D + 8 * li) =
            make_float4(va.x * scale, va.y * scale, va.z * scale, va.w * scale);
        *(float4*)(x + (size_t)r * D + 8 * li + 4) =
            make_float4(vb.x * scale, vb.y * scale, vb.z * scale, vb.w * scale);
        if (li == 0) { logscale[r] = ls; xnorm2[r] = n2 * n2; }
    }
}

// ---------------- per-layer bias precompute ----------------
__global__ void bias_prep(const float* __restrict__ bias, float* __restrict__ bh,
                          float* __restrict__ vvb) {
    int l = blockIdx.x;
    int lane = threadIdx.x;
    float2 b2 = *(const float2*)(bias + (size_t)l * D + 2 * lane);
    float nn = fmaxf(sqrtf(wave_sum(b2.x * b2.x + b2.y * b2.y)), MIN_NORM);
    float s = tanhf(nn) / nn;
    float bx = b2.x * s, by = b2.y * s;
    float pn = sqrtf(wave_sum(bx * bx + by * by));
    float sc = (pn > MAX_NN) ? MAX_NN / fmaxf(pn, MIN_NORM) : 1.0f;
    bx *= sc; by *= sc;
    float vv = wave_sum(bx * bx + by * by);
    *(float2*)(bh + (size_t)l * D + 2 * lane) = make_float2(bx, by);
    if (lane == 0) vvb[l] = vv;
}

// ---------------- W fragment precompute: per-wave hi/lo bf16 fragments ----------------
__global__ __launch_bounds__(256) void wprep(const float* __restrict__ W,
                                             uint4* __restrict__ wh, uint4* __restrict__ wl,
                                             int nlayers) {
    int l = blockIdx.x >> 3;
    int eidx = (blockIdx.x & 7) * 256 + threadIdx.x;  // 0..2047
    if (l >= nlayers) return;
    int lane = eidx & 63;
    int fi = eidx >> 6;            // wid*8 + ki*2 + cf, 0..31
    int wid = fi >> 3, ki = (fi >> 1) & 3, cf = fi & 1;
    int lcol = lane & 15, lkg = lane >> 4;
    int col = wid * 32 + cf * 16 + lcol;
    int krow = ki * 32 + lkg * 8;
    const float* wp = W + (size_t)l * D * D + (size_t)krow * D + col;
    float f[8];
#pragma unroll
    for (int e2 = 0; e2 < 8; ++e2) f[e2] = wp[(size_t)e2 * D];
    unsigned hw[4], lw[4];
#pragma unroll
    for (int p = 0; p < 4; ++p) {
        float a = f[2 * p], b = f[2 * p + 1];
        unsigned h = cvt_pk_bf16(a, b);
        float ha = __uint_as_float(h << 16);
        float hb = __uint_as_float(h & 0xffff0000u);
        hw[p] = h;
        lw[p] = cvt_pk_bf16(a - ha, b - hb);
    }
    size_t off = (size_t)l * 2048 + eidx;
    wh[off] = make_uint4(hw[0], hw[1], hw[2], hw[3]);
    wl[off] = make_uint4(lw[0], lw[1], lw[2], lw[3]);
}

// ---------------- m = (logscale[row] * x[row]) @ W via bf16 MFMA (hi/lo), bf16 output ----
// Barrier-free: each wave loads its own A-fragments directly from global (per-lane
// addressing = MFMA A layout), no LDS. One 32-row tile per block.
__global__ __launch_bounds__(256) void logmap_gemm(const float* __restrict__ x,
                                                   const float* __restrict__ logscale,
                                                   const uint4* __restrict__ wh,
                                                   const uint4* __restrict__ wl,
                                                   unsigned short* __restrict__ m, int n) {
    const int t = threadIdx.x;
    const int wid = t >> 6, lane = t & 63;
    const int lcol = lane & 15, lkg = lane >> 4;
    const int colbase = wid * 32;

    // coalesced pre-converted W fragments
    bf16x8 Bh[4][2], Bl[4][2];
#pragma unroll
    for (int ki = 0; ki < 4; ++ki) {
#pragma unroll
        for (int cf = 0; cf < 2; ++cf) {
            size_t off = (size_t)(wid * 8 + ki * 2 + cf) * 64 + lane;
            uint4 uh = wh[off];
            uint4 ul = wl[off];
            Bh[ki][cf] = *(bf16x8*)&uh;
            Bl[ki][cf] = *(bf16x8*)&ul;
        }
    }

    const int row0 = blockIdx.x * 32;
    // A-fragments direct from global: row = row0 + rf*16 + lcol, k = ki*32 + lkg*8 + e
    bf16x8 Ah[2][4], Al[2][4];
#pragma unroll
    for (int rf = 0; rf < 2; ++rf) {
        int row = row0 + rf * 16 + lcol;
        bool act = (row < n);
        int srow = act ? row : 0;
        float ls = act ? logscale[srow] : 0.f;
        const float* xp = x + (size_t)srow * D + lkg * 8;
#pragma unroll
        for (int ki = 0; ki < 4; ++ki) {
            float v[8];
            *(float4*)&v[0] = *(const float4*)(xp + ki * 32);
            *(float4*)&v[4] = *(const float4*)(xp + ki * 32 + 4);
#pragma unroll
            for (int e2 = 0; e2 < 8; ++e2) v[e2] *= ls;
            unsigned hv[4], lv[4];
#pragma unroll
            for (int pp = 0; pp < 4; ++pp) {
                float a = v[2 * pp], b = v[2 * pp + 1];
                unsigned h = cvt_pk_bf16(a, b);
                float ha = __uint_as_float(h << 16);
                float hb = __uint_as_float(h & 0xffff0000u);
                hv[pp] = h;
                lv[pp] = cvt_pk_bf16(a - ha, b - hb);
            }
            uint4 uh = make_uint4(hv[0], hv[1], hv[2], hv[3]);
            uint4 ul = make_uint4(lv[0], lv[1], lv[2], lv[3]);
            Ah[rf][ki] = *(bf16x8*)&uh;
            Al[rf][ki] = *(bf16x8*)&ul;
        }
    }

    f32x4 acc[2][2];
#pragma unroll
    for (int rf = 0; rf < 2; ++rf)
#pragma unroll
        for (int cf = 0; cf < 2; ++cf) acc[rf][cf] = (f32x4){0.f, 0.f, 0.f, 0.f};

#pragma unroll
    for (int ki = 0; ki < 4; ++ki) {
#pragma unroll
        for (int rf = 0; rf < 2; ++rf)
#pragma unroll
            for (int cf = 0; cf < 2; ++cf) {
                acc[rf][cf] = __builtin_amdgcn_mfma_f32_16x16x32_bf16(Ah[rf][ki], Bh[ki][cf], acc[rf][cf], 0, 0, 0);
                acc[rf][cf] = __builtin_amdgcn_mfma_f32_16x16x32_bf16(Ah[rf][ki], Bl[ki][cf], acc[rf][cf], 0, 0, 0);
                acc[rf][cf] = __builtin_amdgcn_mfma_f32_16x16x32_bf16(Al[rf][ki], Bh[ki][cf], acc[rf][cf], 0, 0, 0);
            }
    }

#pragma unroll
    for (int rf = 0; rf < 2; ++rf)
#pragma unroll
        for (int cf = 0; cf < 2; ++cf)
#pragma unroll
            for (int pr = 0; pr < 2; ++pr) {
                unsigned u = cvt_pk_bf16(acc[rf][cf][2 * pr], acc[rf][cf][2 * pr + 1]);
                int row = row0 + rf * 16 + lkg * 4 + 2 * pr;
                int col = colbase + cf * 16 + lcol;
                if (row < n) m[(size_t)row * D + col] = (unsigned short)u;
                if (row + 1 < n) m[(size_t)(row + 1) * D + col] = (unsigned short)(u >> 16);
            }
}

// ---------------- aggregate + epilogue: 4 rows/wave, padded edge lists ----------
__global__ __launch_bounds__(256) void aggregate(const unsigned short* __restrict__ m,
                                                 const int* __restrict__ row_ptr,
                                                 const Edge* __restrict__ eds,
                                                 const float* __restrict__ bh,
                                                 const float* __restrict__ vvb_p,
                                                 float* __restrict__ x,
                                                 float* __restrict__ logscale,
                                                 float* __restrict__ xnorm2,
                                                 int n, int use_act, int last) {
    int wv = (int)((blockIdx.x * (size_t)blockDim.x + threadIdx.x) >> 6);
    int lane = threadIdx.x & 63;
    int q = lane >> 4, li = lane & 15;
    if (wv * 4 >= n) return;
    int r = wv * 4 + q;
    bool active = (r < n);

    int beg = 0, end = 0;
    if (active) { beg = row_ptr[r]; end = row_ptr[r + 1]; }

    float vv = active ? xnorm2[r] : 0.f;
    float4 xa = active ? *(const float4*)(x + (size_t)r * D + 8 * li)
                       : make_float4(0.f, 0.f, 0.f, 0.f);
    float4 xb = active ? *(const float4*)(x + (size_t)r * D + 8 * li + 4)
                       : make_float4(0.f, 0.f, 0.f, 0.f);

    const char* mB = (const char*)m + ((size_t)li << 4);
    float2 A01 = bc2(0.f), A23 = bc2(0.f), A45 = bc2(0.f), A67 = bc2(0.f);
    int e = beg;
    for (; e + 8 <= end; e += 8) {
#pragma unroll
        for (int j = 0; j < 8; ++j) {
            Edge ee = eds[e + j];
            uint4 g = *(const uint4*)(mB + ((size_t)(unsigned)ee.c << 8));
            float2 v = bc2(ee.v);
            A01 = pk_fma2(up2(g.x), v, A01); A23 = pk_fma2(up2(g.y), v, A23);
            A45 = pk_fma2(up2(g.z), v, A45); A67 = pk_fma2(up2(g.w), v, A67);
        }
    }
    if (e < end) {
#pragma unroll
        for (int j = 0; j < 4; ++j) {
            Edge ee = eds[e + j];
            uint4 g = *(const uint4*)(mB + ((size_t)(unsigned)ee.c << 8));
            float2 v = bc2(ee.v);
            A01 = pk_fma2(up2(g.x), v, A01); A23 = pk_fma2(up2(g.y), v, A23);
            A45 = pk_fma2(up2(g.z), v, A45); A67 = pk_fma2(up2(g.w), v, A67);
        }
    }

    float4 bv0 = *(const float4*)(bh + 8 * li);
    float4 bv1 = *(const float4*)(bh + 8 * li + 4);
    float2 b01 = mk2(bv0.x, bv0.y), b23 = mk2(bv0.z, bv0.w);
    float2 b45 = mk2(bv1.x, bv1.y), b67 = mk2(bv1.z, bv1.w);
    float vvb = *vvb_p;

    float2 daa = pk_fma2(A67, A67, pk_fma2(A45, A45, pk_fma2(A23, A23, pk_mul2(A01, A01))));
    float2 dab = pk_fma2(A67, b67, pk_fma2(A45, b45, pk_fma2(A23, b23, pk_mul2(A01, b01))));
    float saa = daa.x + daa.y, sab = dab.x + dab.y;
    g16sum2(saa, sab);

    float na = fmaxf(fsqrt_(saa), MIN_NORM);
    float th = tanh_pos(na);
    float s1 = th * frcp(na);
    float nh = th;
    if (th > MAX_NN) { s1 *= MAX_NN * frcp(th); nh = MAX_NN; }
    float2 vs1 = bc2(s1);
    float2 H01 = pk_mul2(A01, vs1), H23 = pk_mul2(A23, vs1);
    float2 H45 = pk_mul2(A45, vs1), H67 = pk_mul2(A67, vs1);
    float uu = nh * nh;
    float uv = s1 * sab;

    float ca = 1.f + 2.f * uv + vvb;
    float cb = 1.f - uu;
    float den = fmaxf(1.f + 2.f * uv + uu * vvb, MIN_NORM);
    float nsq = fmaxf(ca * ca * uu + 2.f * ca * cb * uv + cb * cb * vvb, 0.f);
    float rden = frcp(den);
    float n2 = fsqrt_(nsq) * rden;
    float s2 = rden;
    if (n2 > MAX_NN) { s2 *= MAX_NN * frcp(n2); n2 = MAX_NN; }
    float2 vca = bc2(ca), vcb = bc2(cb), vs2 = bc2(s2);
    float2 P01 = pk_mul2(pk_fma2(H01, vca, pk_mul2(b01, vcb)), vs2);
    float2 P23 = pk_mul2(pk_fma2(H23, vca, pk_mul2(b23, vcb)), vs2);
    float2 P45 = pk_mul2(pk_fma2(H45, vca, pk_mul2(b45, vcb)), vs2);
    float2 P67 = pk_mul2(pk_fma2(H67, vca, pk_mul2(b67, vcb)), vs2);

    float2 xo01 = mk2(xa.x, xa.y), xo23 = mk2(xa.z, xa.w);
    float2 xo45 = mk2(xb.x, xb.y), xo67 = mk2(xb.z, xb.w);

    float2 Q01, Q23, Q45, Q67;
    float uu3, uv3;
    if (use_act) {
        float nnv = fmaxf(n2, MIN_NORM);
        float nc = fminf(fmaxf(n2, MIN_NORM), MAX_NN);
        float ls2 = atanh_clip(nc) * frcp(nnv);
        float2 vls = bc2(ls2);
        float2 Z01 = pk_mul2(P01, vls), Z23 = pk_mul2(P23, vls);
        float2 Z45 = pk_mul2(P45, vls), Z67 = pk_mul2(P67, vls);
        float2 T01 = mk2(tanh_sgn(Z01.x), tanh_sgn(Z01.y));
        float2 T23 = mk2(tanh_sgn(Z23.x), tanh_sgn(Z23.y));
        float2 T45 = mk2(tanh_sgn(Z45.x), tanh_sgn(Z45.y));
        float2 T67 = mk2(tanh_sgn(Z67.x), tanh_sgn(Z67.y));
        float2 dtt = pk_fma2(T67, T67, pk_fma2(T45, T45, pk_fma2(T23, T23, pk_mul2(T01, T01))));
        float2 dtx = pk_fma2(T67, xo67, pk_fma2(T45, xo45, pk_fma2(T23, xo23, pk_mul2(T01, xo01))));
        float stt = dtt.x + dtt.y, stx = dtx.x + dtx.y;
        g16sum2(stt, stx);
        float n3 = fmaxf(fsqrt_(stt), MIN_NORM);
        float th3 = tanh_pos(n3);
        float s3 = th3 * frcp(n3);
        float nh3 = th3;
        if (th3 > MAX_NN) { s3 *= MAX_NN * frcp(th3); nh3 = MAX_NN; }
        float2 vs3 = bc2(s3);
        Q01 = pk_mul2(T01, vs3); Q23 = pk_mul2(T23, vs3);
        Q45 = pk_mul2(T45, vs3); Q67 = pk_mul2(T67, vs3);
        uu3 = nh3 * nh3;
        uv3 = s3 * stx;
    } else {
        float2 dpx = pk_fma2(P67, xo67, pk_fma2(P45, xo45, pk_fma2(P23, xo23, pk_mul2(P01, xo01))));
        float suv = g16sum(dpx.x + dpx.y);
        Q01 = P01; Q23 = P23; Q45 = P45; Q67 = P67;
        uu3 = n2 * n2;
        uv3 = suv;
    }

    ca = 1.f + 2.f * uv3 + vv;
    cb = 1.f - uu3;
    den = fmaxf(1.f + 2.f * uv3 + uu3 * vv, MIN_NORM);
    nsq = fmaxf(ca * ca * uu3 + 2.f * ca * cb * uv3 + cb * cb * vv, 0.f);
    rden = frcp(den);
    float n4 = fsqrt_(nsq) * rden;
    float s4 = rden;
    if (n4 > MAX_NN) { s4 *= MAX_NN * frcp(n4); n4 = MAX_NN; }
    float2 vca2 = bc2(ca), vcb2 = bc2(cb), vs4 = bc2(s4);
    float2 O01 = pk_mul2(pk_fma2(Q01, vca2, pk_mul2(xo01, vcb2)), vs4);
    float2 O23 = pk_mul2(pk_fma2(Q23, vca2, pk_mul2(xo23, vcb2)), vs4);
    float2 O45 = pk_mul2(pk_fma2(Q45, vca2, pk_mul2(xo45, vcb2)), vs4);
    float2 O67 = pk_mul2(pk_fma2(Q67, vca2, pk_mul2(xo67, vcb2)), vs4);

    if (active) {
        *(float4*)(x + (size_t)r * D + 8 * li) = make_float4(O01.x, O01.y, O23.x, O23.y);
        *(float4*)(x + (size_t)r * D + 8 * li + 4) = make_float4(O45.x, O45.y, O67.x, O67.y);
        if (li == 0) {
            xnorm2[r] = n4 * n4;
            if (!last) {
                float nnv = fmaxf(n4, MIN_NORM);
                float nc = fminf(fmaxf(n4, MIN_NORM), MAX_NN);
                logscale[r] = atanh_clip(nc) * frcp(nnv);
            }
        }
    }
}

extern "C" void kernel_launch(void* const* d_in, const int* in_sizes, int n_in,
                              void* d_out, int out_size, void* d_ws, size_t ws_size,
                              hipStream_t stream) {
    const float* ent  = (const float*)d_in[0];
    const float* W    = (const float*)d_in[1];
    const float* bias = (const float*)d_in[2];
    const int* rows   = (const int*)d_in[3];
    const int* cols   = (const int*)d_in[4];
    const float* vals = (const float*)d_in[5];
    float* x = (float*)d_out;

    const int n = in_sizes[0] / D;
    const int e = in_sizes[3];
    const int nlayers = in_sizes[1] / (D * D);
    const int npart = (n + ROWS_PER_BLOCK - 1) / ROWS_PER_BLOCK;
    const int ntiles = (n + 31) / 32;
    const size_t e_cap = (size_t)e + 3u * (size_t)n;

    char* ws = (char*)d_ws;
    size_t off = 0;
    auto alloc = [&](size_t bytes) {
        void* p = ws + off;
        off += (bytes + 255) & ~(size_t)255;
        return p;
    };
    unsigned short* m = (unsigned short*)alloc((size_t)n * D * sizeof(unsigned short));
    float* logscale = (float*)alloc((size_t)n * sizeof(float));
    float* xnorm2   = (float*)alloc((size_t)n * sizeof(float));
    int*   counts   = (int*)alloc((size_t)n * sizeof(int));
    int*   row_ptr  = (int*)alloc((size_t)(n + 1) * sizeof(int));
    int*   cursor   = (int*)alloc((size_t)n * sizeof(int));
    int*   partials = (int*)alloc((size_t)(npart > 1024 ? npart : 1024) * sizeof(int));
    float* bhb      = (float*)alloc((size_t)nlayers * D * sizeof(float));
    float* vvb      = (float*)alloc((size_t)nlayers * sizeof(float));
    uint4* whb      = (uint4*)alloc((size_t)nlayers * 2048 * sizeof(uint4));
    uint4* wlb      = (uint4*)alloc((size_t)nlayers * 2048 * sizeof(uint4));
    Edge*  eds      = (Edge*)alloc(e_cap * sizeof(Edge));

    hipMemsetAsync(counts, 0, (size_t)n * sizeof(int), stream);
    hipMemsetAsync(eds, 0, e_cap * sizeof(Edge), stream);
    hist_kernel<<<(e + 255) / 256, 256, 0, stream>>>(rows, counts, e);
    partial_kernel<<<npart, 256, 0, stream>>>(counts, partials, n);
    scan_partials<<<1, 1024, 0, stream>>>(partials, npart);
    rowptr_kernel<<<npart, 256, 0, stream>>>(counts, partials, row_ptr, cursor, n);
    scatter_kernel<<<(e + 255) / 256, 256, 0, stream>>>(rows, cols, vals, cursor, eds, e);

    bias_prep<<<nlayers, 64, 0, stream>>>(bias, bhb, vvb);
    wprep<<<nlayers * 8, 256, 0, stream>>>(W, whb, wlb, nlayers);
    proj_init<<<(n + 15) / 16, 256, 0, stream>>>(ent, x, logscale, xnorm2, n);

    for (int l = 0; l < nlayers; ++l) {
        logmap_gemm<<<ntiles, 256, 0, stream>>>(x, logscale,
                                                whb + (size_t)l * 2048,
                                                wlb + (size_t)l * 2048, m, n);
        int use_act = (l < nlayers - 1) ? 1 : 0;
        aggregate<<<(n + 15) / 16, 256, 0, stream>>>(m, row_ptr, eds, bhb + (size_t)l * D,
                                                     vvb + l, x, logscale, xnorm2, n,
                                                     use_act, (l == nlayers - 1) ? 1 : 0);
    }
}

// Round 17
// 261.047 us; speedup vs baseline: 1.1138x; 1.1138x over previous
//
#include <hip/hip_runtime.h>
#include <math.h>

#define D 128
#define PROJ_EPS 1e-5f
#define MAX_NN (1.0f - PROJ_EPS)
#define MIN_NORM 1e-15f
#define ROWS_PER_BLOCK 2048

struct __align__(8) Edge { int c; float v; };

typedef __attribute__((ext_vector_type(8))) short bf16x8;
typedef __attribute__((ext_vector_type(4))) float f32x4;

// packed f32->bf16 RNE convert: dst.lo = bf16(a), dst.hi = bf16(b)
__device__ inline unsigned cvt_pk_bf16(float a, float b) {
    unsigned r;
    asm("v_cvt_pk_bf16_f32 %0, %1, %2" : "=v"(r) : "v"(a), "v"(b));
    return r;
}

__device__ inline float wave_sum(float v) {
#pragma unroll
    for (int off = 32; off; off >>= 1) v += __shfl_xor(v, off, 64);
    return v;
}
// 16-lane-group reductions
__device__ inline float g16sum(float v) {
#pragma unroll
    for (int off = 8; off; off >>= 1) v += __shfl_xor(v, off, 64);
    return v;
}
__device__ inline void g16sum2(float& a, float& b) {
#pragma unroll
    for (int off = 8; off; off >>= 1) {
        a += __shfl_xor(a, off, 64);
        b += __shfl_xor(b, off, 64);
    }
}
__device__ inline float frcp(float x) { return __builtin_amdgcn_rcpf(x); }
__device__ inline float fsqrt_(float x) { return __builtin_amdgcn_sqrtf(x); }
__device__ inline float tanh_pos(float x) {
    float e = __expf(-2.f * x);
    return (1.f - e) * frcp(1.f + e);
}
__device__ inline float tanh_sgn(float x) {
    float ax = fabsf(x);
    float e = __expf(-2.f * ax);
    float r = (1.f - e) * frcp(1.f + e);
    return copysignf(r, x);
}
__device__ inline float atanh_clip(float x) {
    return 0.5f * __logf((1.f + x) * frcp(1.f - x));
}

// ---- packed-f32 pair ops ----
__device__ inline float2 mk2(float a, float b) { float2 r; r.x = a; r.y = b; return r; }
__device__ inline float2 bc2(float a) { return mk2(a, a); }
__device__ inline float2 pk_fma2(float2 a, float2 b, float2 c) {
    float2 d;
    asm("v_pk_fma_f32 %0, %1, %2, %3" : "=v"(d) : "v"(a), "v"(b), "v"(c));
    return d;
}
__device__ inline float2 pk_mul2(float2 a, float2 b) {
    float2 d;
    asm("v_pk_mul_f32 %0, %1, %2" : "=v"(d) : "v"(a), "v"(b));
    return d;
}
__device__ inline float2 up2(unsigned u) {
    uint2 t; t.x = u << 16; t.y = u & 0xffff0000u;
    float2 r; r.x = __uint_as_float(t.x); r.y = __uint_as_float(t.y);
    return r;
}

// ---------------- CSR build ----------------
__global__ void hist_kernel(const int* __restrict__ rows, int* __restrict__ counts, int e) {
    int i = blockIdx.x * blockDim.x + threadIdx.x;
    if (i < e) atomicAdd(&counts[rows[i]], 1);
}

__global__ __launch_bounds__(256) void partial_kernel(const int* __restrict__ counts,
                                                      int* __restrict__ partials, int n) {
    int t = threadIdx.x;
    int start = blockIdx.x * ROWS_PER_BLOCK + t * 8;
    int s = 0;
#pragma unroll
    for (int j = 0; j < 8; ++j) {
        int i = start + j;
        if (i < n) s += (counts[i] + 3) & ~3;
    }
    int lane = t & 63, wv = t >> 6;
#pragma unroll
    for (int o = 32; o; o >>= 1) s += __shfl_xor(s, o, 64);
    __shared__ int wsum[4];
    if (lane == 0) wsum[wv] = s;
    __syncthreads();
    if (t == 0) partials[blockIdx.x] = wsum[0] + wsum[1] + wsum[2] + wsum[3];
}

__global__ void scan_partials(int* __restrict__ partials, int npart) {
    __shared__ int buf[1024];
    int t = threadIdx.x;
    int v = (t < npart) ? partials[t] : 0;
    buf[t] = v;
    __syncthreads();
    for (int o = 1; o < 1024; o <<= 1) {
        int x = (t >= o) ? buf[t - o] : 0;
        __syncthreads();
        buf[t] += x;
        __syncthreads();
    }
    if (t < npart) partials[t] = buf[t] - v;
}

__global__ __launch_bounds__(256) void rowptr_kernel(const int* __restrict__ counts,
                                                     const int* __restrict__ partials,
                                                     int* __restrict__ row_ptr,
                                                     int* __restrict__ cursor, int n) {
    int t = threadIdx.x;
    int start = blockIdx.x * ROWS_PER_BLOCK + t * 8;
    int c[8];
    int s = 0;
#pragma unroll
    for (int j = 0; j < 8; ++j) {
        int i = start + j;
        c[j] = (i < n) ? ((counts[i] + 3) & ~3) : 0;
        s += c[j];
    }
    int lane = t & 63, wv = t >> 6;
    int inc = s;
#pragma unroll
    for (int o = 1; o < 64; o <<= 1) {
        int tt = __shfl_up(inc, o, 64);
        if (lane >= o) inc += tt;
    }
    __shared__ int wsum[4];
    if (lane == 63) wsum[wv] = inc;
    __syncthreads();
    if (t == 0) {
        int acc = 0;
        for (int w = 0; w < 4; ++w) { int tmp = wsum[w]; wsum[w] = acc; acc += tmp; }
    }
    __syncthreads();
    int run = partials[blockIdx.x] + wsum[wv] + (inc - s);
#pragma unroll
    for (int j = 0; j < 8; ++j) {
        int i = start + j;
        if (i < n) {
            row_ptr[i] = run;
            cursor[i] = run;
            run += c[j];
            if (i == n - 1) row_ptr[n] = run;
        }
    }
}

__global__ void scatter_kernel(const int* __restrict__ rows, const int* __restrict__ cols,
                               const float* __restrict__ vals, int* __restrict__ cursor,
                               Edge* __restrict__ eds, int e) {
    int i = blockIdx.x * blockDim.x + threadIdx.x;
    if (i < e) {
        int r = rows[i];
        int pos = atomicAdd(&cursor[r], 1);
        Edge ed; ed.c = cols[i]; ed.v = vals[i];
        eds[pos] = ed;
    }
}

// ---------------- init: x = proj(ent), logscale, xnorm2 (4 rows/wave) ----------------
__global__ __launch_bounds__(256) void proj_init(const float* __restrict__ ent,
                                                 float* __restrict__ x,
                                                 float* __restrict__ logscale,
                                                 float* __restrict__ xnorm2, int n) {
    int wv = (int)((blockIdx.x * (size_t)blockDim.x + threadIdx.x) >> 6);
    int lane = threadIdx.x & 63;
    int q = lane >> 4, li = lane & 15;
    if (wv * 4 >= n) return;
    int r = wv * 4 + q;
    bool active = (r < n);
    float4 va = active ? *(const float4*)(ent + (size_t)r * D + 8 * li)
                       : make_float4(0.f, 0.f, 0.f, 0.f);
    float4 vb = active ? *(const float4*)(ent + (size_t)r * D + 8 * li + 4)
                       : make_float4(0.f, 0.f, 0.f, 0.f);
    float ss = va.x * va.x + va.y * va.y + va.z * va.z + va.w * va.w
             + vb.x * vb.x + vb.y * vb.y + vb.z * vb.z + vb.w * vb.w;
    ss = g16sum(ss);
    float nrm = fsqrt_(ss);
    float scale = (nrm > MAX_NN) ? MAX_NN * frcp(fmaxf(nrm, MIN_NORM)) : 1.0f;
    float n2 = fminf(nrm, MAX_NN);  // == ||x*scale|| analytically
    float nc = fminf(fmaxf(n2, MIN_NORM), MAX_NN);
    float ls = atanh_clip(nc) * frcp(fmaxf(n2, MIN_NORM));
    if (active) {
        *(float4*)(x + (size_t)r * D + 8 * li) =
            make_float4(va.x * scale, va.y * scale, va.z * scale, va.w * scale);
        *(float4*)(x + (size_t)r * D + 8 * li + 4) =
            make_float4(vb.x * scale, vb.y * scale, vb.z * scale, vb.w * scale);
        if (li == 0) { logscale[r] = ls; xnorm2[r] = n2 * n2; }
    }
}

// ---------------- per-layer bias precompute ----------------
__global__ void bias_prep(const float* __restrict__ bias, float* __restrict__ bh,
                          float* __restrict__ vvb) {
    int l = blockIdx.x;
    int lane = threadIdx.x;
    float2 b2 = *(const float2*)(bias + (size_t)l * D + 2 * lane);
    float nn = fmaxf(sqrtf(wave_sum(b2.x * b2.x + b2.y * b2.y)), MIN_NORM);
    float s = tanhf(nn) / nn;
    float bx = b2.x * s, by = b2.y * s;
    float pn = sqrtf(wave_sum(bx * bx + by * by));
    float sc = (pn > MAX_NN) ? MAX_NN / fmaxf(pn, MIN_NORM) : 1.0f;
    bx *= sc; by *= sc;
    float vv = wave_sum(bx * bx + by * by);
    *(float2*)(bh + (size_t)l * D + 2 * lane) = make_float2(bx, by);
    if (lane == 0) vvb[l] = vv;
}

// ---------------- W fragment precompute: per-wave hi/lo bf16 fragments ----------------
// Entry layout: entry = (wid*8 + ki*2 + cf)*64 + lane; 16B hi + 16B lo each.
// 2048 entries per layer. In gemm, wave wid / lane loads entry coalesced.
__global__ __launch_bounds__(256) void wprep(const float* __restrict__ W,
                                             uint4* __restrict__ wh, uint4* __restrict__ wl,
                                             int nlayers) {
    int l = blockIdx.x >> 3;
    int eidx = (blockIdx.x & 7) * 256 + threadIdx.x;  // 0..2047
    if (l >= nlayers) return;
    int lane = eidx & 63;
    int fi = eidx >> 6;            // wid*8 + ki*2 + cf, 0..31
    int wid = fi >> 3, ki = (fi >> 1) & 3, cf = fi & 1;
    int lcol = lane & 15, lkg = lane >> 4;
    int col = wid * 32 + cf * 16 + lcol;
    int krow = ki * 32 + lkg * 8;
    const float* wp = W + (size_t)l * D * D + (size_t)krow * D + col;
    float f[8];
#pragma unroll
    for (int e2 = 0; e2 < 8; ++e2) f[e2] = wp[(size_t)e2 * D];
    unsigned hw[4], lw[4];
#pragma unroll
    for (int p = 0; p < 4; ++p) {
        float a = f[2 * p], b = f[2 * p + 1];
        unsigned h = cvt_pk_bf16(a, b);
        float ha = __uint_as_float(h << 16);
        float hb = __uint_as_float(h & 0xffff0000u);
        hw[p] = h;
        lw[p] = cvt_pk_bf16(a - ha, b - hb);
    }
    size_t off = (size_t)l * 2048 + eidx;
    wh[off] = make_uint4(hw[0], hw[1], hw[2], hw[3]);
    wl[off] = make_uint4(lw[0], lw[1], lw[2], lw[3]);
}

// ---------------- m = (logscale[row] * x[row]) @ W via bf16 MFMA (hi/lo), bf16 output ----
// One 32-row tile per block (grid = ntiles); W fragments pre-converted (wprep).
__global__ __launch_bounds__(256) void logmap_gemm(const float* __restrict__ x,
                                                   const float* __restrict__ logscale,
                                                   const uint4* __restrict__ wh,
                                                   const uint4* __restrict__ wl,
                                                   unsigned short* __restrict__ m, int n) {
    __shared__ char lds[16384];
    const int t = threadIdx.x;
    const int wid = t >> 6, lane = t & 63;
    const int lcol = lane & 15, lkg = lane >> 4;
    const int colbase = wid * 32;

    // coalesced pre-converted W fragments
    bf16x8 Bh[4][2], Bl[4][2];
#pragma unroll
    for (int ki = 0; ki < 4; ++ki) {
#pragma unroll
        for (int cf = 0; cf < 2; ++cf) {
            size_t off = (size_t)(wid * 8 + ki * 2 + cf) * 64 + lane;
            uint4 uh = wh[off];
            uint4 ul = wl[off];
            Bh[ki][cf] = *(bf16x8*)&uh;
            Bl[ki][cf] = *(bf16x8*)&ul;
        }
    }

    const int row0 = blockIdx.x * 32;
#pragma unroll
    for (int p = t; p < 512; p += 256) {
        int fi = p >> 6, ln = p & 63;
        int rf = fi >> 2, ki = fi & 3;
        int row = row0 + rf * 16 + (ln & 15);
        int k0 = ki * 32 + (ln >> 4) * 8;
        float v[8];
        if (row < n) {
            float ls = logscale[row];
            const float* xp = x + (size_t)row * D + k0;
            *(float4*)&v[0] = *(const float4*)xp;
            *(float4*)&v[4] = *(const float4*)(xp + 4);
#pragma unroll
            for (int e2 = 0; e2 < 8; ++e2) v[e2] *= ls;
        } else {
#pragma unroll
            for (int e2 = 0; e2 < 8; ++e2) v[e2] = 0.f;
        }
        unsigned hv[4], lv[4];
#pragma unroll
        for (int pp = 0; pp < 4; ++pp) {
            float a = v[2 * pp], b = v[2 * pp + 1];
            unsigned h = cvt_pk_bf16(a, b);
            float ha = __uint_as_float(h << 16);
            float hb = __uint_as_float(h & 0xffff0000u);
            hv[pp] = h;
            lv[pp] = cvt_pk_bf16(a - ha, b - hb);
        }
        *(uint4*)(lds + fi * 1024 + ln * 16) = make_uint4(hv[0], hv[1], hv[2], hv[3]);
        *(uint4*)(lds + 8192 + fi * 1024 + ln * 16) = make_uint4(lv[0], lv[1], lv[2], lv[3]);
    }
    __syncthreads();

    f32x4 acc[2][2];
#pragma unroll
    for (int rf = 0; rf < 2; ++rf)
#pragma unroll
        for (int cf = 0; cf < 2; ++cf) acc[rf][cf] = (f32x4){0.f, 0.f, 0.f, 0.f};

#pragma unroll
    for (int ki = 0; ki < 4; ++ki) {
        bf16x8 Ah[2], Al[2];
#pragma unroll
        for (int rf = 0; rf < 2; ++rf) {
            Ah[rf] = *(const bf16x8*)(lds + (rf * 4 + ki) * 1024 + lane * 16);
            Al[rf] = *(const bf16x8*)(lds + 8192 + (rf * 4 + ki) * 1024 + lane * 16);
        }
#pragma unroll
        for (int rf = 0; rf < 2; ++rf)
#pragma unroll
            for (int cf = 0; cf < 2; ++cf) {
                acc[rf][cf] = __builtin_amdgcn_mfma_f32_16x16x32_bf16(Ah[rf], Bh[ki][cf], acc[rf][cf], 0, 0, 0);
                acc[rf][cf] = __builtin_amdgcn_mfma_f32_16x16x32_bf16(Ah[rf], Bl[ki][cf], acc[rf][cf], 0, 0, 0);
                acc[rf][cf] = __builtin_amdgcn_mfma_f32_16x16x32_bf16(Al[rf], Bh[ki][cf], acc[rf][cf], 0, 0, 0);
            }
    }

#pragma unroll
    for (int rf = 0; rf < 2; ++rf)
#pragma unroll
        for (int cf = 0; cf < 2; ++cf)
#pragma unroll
            for (int pr = 0; pr < 2; ++pr) {
                unsigned u = cvt_pk_bf16(acc[rf][cf][2 * pr], acc[rf][cf][2 * pr + 1]);
                int row = row0 + rf * 16 + lkg * 4 + 2 * pr;
                int col = colbase + cf * 16 + lcol;
                if (row < n) m[(size_t)row * D + col] = (unsigned short)u;
                if (row + 1 < n) m[(size_t)(row + 1) * D + col] = (unsigned short)(u >> 16);
            }
}

// ---------------- aggregate + epilogue: 4 rows/wave, padded edge lists ----------
__global__ __launch_bounds__(256) void aggregate(const unsigned short* __restrict__ m,
                                                 const int* __restrict__ row_ptr,
                                                 const Edge* __restrict__ eds,
                                                 const float* __restrict__ bh,
                                                 const float* __restrict__ vvb_p,
                                                 float* __restrict__ x,
                                                 float* __restrict__ logscale,
                                                 float* __restrict__ xnorm2,
                                                 int n, int use_act, int last) {
    int wv = (int)((blockIdx.x * (size_t)blockDim.x + threadIdx.x) >> 6);
    int lane = threadIdx.x & 63;
    int q = lane >> 4, li = lane & 15;
    if (wv * 4 >= n) return;
    int r = wv * 4 + q;
    bool active = (r < n);

    int beg = 0, end = 0;
    if (active) { beg = row_ptr[r]; end = row_ptr[r + 1]; }

    float vv = active ? xnorm2[r] : 0.f;
    float4 xa = active ? *(const float4*)(x + (size_t)r * D + 8 * li)
                       : make_float4(0.f, 0.f, 0.f, 0.f);
    float4 xb = active ? *(const float4*)(x + (size_t)r * D + 8 * li + 4)
                       : make_float4(0.f, 0.f, 0.f, 0.f);

    const char* mB = (const char*)m + ((size_t)li << 4);
    float2 A01 = bc2(0.f), A23 = bc2(0.f), A45 = bc2(0.f), A67 = bc2(0.f);
    int e = beg;
    for (; e + 8 <= end; e += 8) {
#pragma unroll
        for (int j = 0; j < 8; ++j) {
            Edge ee = eds[e + j];
            uint4 g = *(const uint4*)(mB + ((size_t)(unsigned)ee.c << 8));
            float2 v = bc2(ee.v);
            A01 = pk_fma2(up2(g.x), v, A01); A23 = pk_fma2(up2(g.y), v, A23);
            A45 = pk_fma2(up2(g.z), v, A45); A67 = pk_fma2(up2(g.w), v, A67);
        }
    }
    if (e < end) {
#pragma unroll
        for (int j = 0; j < 4; ++j) {
            Edge ee = eds[e + j];
            uint4 g = *(const uint4*)(mB + ((size_t)(unsigned)ee.c << 8));
            float2 v = bc2(ee.v);
            A01 = pk_fma2(up2(g.x), v, A01); A23 = pk_fma2(up2(g.y), v, A23);
            A45 = pk_fma2(up2(g.z), v, A45); A67 = pk_fma2(up2(g.w), v, A67);
        }
    }

    float4 bv0 = *(const float4*)(bh + 8 * li);
    float4 bv1 = *(const float4*)(bh + 8 * li + 4);
    float2 b01 = mk2(bv0.x, bv0.y), b23 = mk2(bv0.z, bv0.w);
    float2 b45 = mk2(bv1.x, bv1.y), b67 = mk2(bv1.z, bv1.w);
    float vvb = *vvb_p;

    float2 daa = pk_fma2(A67, A67, pk_fma2(A45, A45, pk_fma2(A23, A23, pk_mul2(A01, A01))));
    float2 dab = pk_fma2(A67, b67, pk_fma2(A45, b45, pk_fma2(A23, b23, pk_mul2(A01, b01))));
    float saa = daa.x + daa.y, sab = dab.x + dab.y;
    g16sum2(saa, sab);

    float na = fmaxf(fsqrt_(saa), MIN_NORM);
    float th = tanh_pos(na);
    float s1 = th * frcp(na);
    float nh = th;
    if (th > MAX_NN) { s1 *= MAX_NN * frcp(th); nh = MAX_NN; }
    float2 vs1 = bc2(s1);
    float2 H01 = pk_mul2(A01, vs1), H23 = pk_mul2(A23, vs1);
    float2 H45 = pk_mul2(A45, vs1), H67 = pk_mul2(A67, vs1);
    float uu = nh * nh;
    float uv = s1 * sab;

    float ca = 1.f + 2.f * uv + vvb;
    float cb = 1.f - uu;
    float den = fmaxf(1.f + 2.f * uv + uu * vvb, MIN_NORM);
    float nsq = fmaxf(ca * ca * uu + 2.f * ca * cb * uv + cb * cb * vvb, 0.f);
    float rden = frcp(den);
    float n2 = fsqrt_(nsq) * rden;
    float s2 = rden;
    if (n2 > MAX_NN) { s2 *= MAX_NN * frcp(n2); n2 = MAX_NN; }
    float2 vca = bc2(ca), vcb = bc2(cb), vs2 = bc2(s2);
    float2 P01 = pk_mul2(pk_fma2(H01, vca, pk_mul2(b01, vcb)), vs2);
    float2 P23 = pk_mul2(pk_fma2(H23, vca, pk_mul2(b23, vcb)), vs2);
    float2 P45 = pk_mul2(pk_fma2(H45, vca, pk_mul2(b45, vcb)), vs2);
    float2 P67 = pk_mul2(pk_fma2(H67, vca, pk_mul2(b67, vcb)), vs2);

    float2 xo01 = mk2(xa.x, xa.y), xo23 = mk2(xa.z, xa.w);
    float2 xo45 = mk2(xb.x, xb.y), xo67 = mk2(xb.z, xb.w);

    float2 Q01, Q23, Q45, Q67;
    float uu3, uv3;
    if (use_act) {
        float nnv = fmaxf(n2, MIN_NORM);
        float nc = fminf(fmaxf(n2, MIN_NORM), MAX_NN);
        float ls2 = atanh_clip(nc) * frcp(nnv);
        float2 vls = bc2(ls2);
        float2 Z01 = pk_mul2(P01, vls), Z23 = pk_mul2(P23, vls);
        float2 Z45 = pk_mul2(P45, vls), Z67 = pk_mul2(P67, vls);
        float2 T01 = mk2(tanh_sgn(Z01.x), tanh_sgn(Z01.y));
        float2 T23 = mk2(tanh_sgn(Z23.x), tanh_sgn(Z23.y));
        float2 T45 = mk2(tanh_sgn(Z45.x), tanh_sgn(Z45.y));
        float2 T67 = mk2(tanh_sgn(Z67.x), tanh_sgn(Z67.y));
        float2 dtt = pk_fma2(T67, T67, pk_fma2(T45, T45, pk_fma2(T23, T23, pk_mul2(T01, T01))));
        float2 dtx = pk_fma2(T67, xo67, pk_fma2(T45, xo45, pk_fma2(T23, xo23, pk_mul2(T01, xo01))));
        float stt = dtt.x + dtt.y, stx = dtx.x + dtx.y;
        g16sum2(stt, stx);
        float n3 = fmaxf(fsqrt_(stt), MIN_NORM);
        float th3 = tanh_pos(n3);
        float s3 = th3 * frcp(n3);
        float nh3 = th3;
        if (th3 > MAX_NN) { s3 *= MAX_NN * frcp(th3); nh3 = MAX_NN; }
        float2 vs3 = bc2(s3);
        Q01 = pk_mul2(T01, vs3); Q23 = pk_mul2(T23, vs3);
        Q45 = pk_mul2(T45, vs3); Q67 = pk_mul2(T67, vs3);
        uu3 = nh3 * nh3;
        uv3 = s3 * stx;
    } else {
        float2 dpx = pk_fma2(P67, xo67, pk_fma2(P45, xo45, pk_fma2(P23, xo23, pk_mul2(P01, xo01))));
        float suv = g16sum(dpx.x + dpx.y);
        Q01 = P01; Q23 = P23; Q45 = P45; Q67 = P67;
        uu3 = n2 * n2;
        uv3 = suv;
    }

    ca = 1.f + 2.f * uv3 + vv;
    cb = 1.f - uu3;
    den = fmaxf(1.f + 2.f * uv3 + uu3 * vv, MIN_NORM);
    nsq = fmaxf(ca * ca * uu3 + 2.f * ca * cb * uv3 + cb * cb * vv, 0.f);
    rden = frcp(den);
    float n4 = fsqrt_(nsq) * rden;
    float s4 = rden;
    if (n4 > MAX_NN) { s4 *= MAX_NN * frcp(n4); n4 = MAX_NN; }
    float2 vca2 = bc2(ca), vcb2 = bc2(cb), vs4 = bc2(s4);
    float2 O01 = pk_mul2(pk_fma2(Q01, vca2, pk_mul2(xo01, vcb2)), vs4);
    float2 O23 = pk_mul2(pk_fma2(Q23, vca2, pk_mul2(xo23, vcb2)), vs4);
    float2 O45 = pk_mul2(pk_fma2(Q45, vca2, pk_mul2(xo45, vcb2)), vs4);
    float2 O67 = pk_mul2(pk_fma2(Q67, vca2, pk_mul2(xo67, vcb2)), vs4);

    if (active) {
        *(float4*)(x + (size_t)r * D + 8 * li) = make_float4(O01.x, O01.y, O23.x, O23.y);
        *(float4*)(x + (size_t)r * D + 8 * li + 4) = make_float4(O45.x, O45.y, O67.x, O67.y);
        if (li == 0) {
            xnorm2[r] = n4 * n4;
            if (!last) {
                float nnv = fmaxf(n4, MIN_NORM);
                float nc = fminf(fmaxf(n4, MIN_NORM), MAX_NN);
                logscale[r] = atanh_clip(nc) * frcp(nnv);
            }
        }
    }
}

extern "C" void kernel_launch(void* const* d_in, const int* in_sizes, int n_in,
                              void* d_out, int out_size, void* d_ws, size_t ws_size,
                              hipStream_t stream) {
    const float* ent  = (const float*)d_in[0];
    const float* W    = (const float*)d_in[1];
    const float* bias = (const float*)d_in[2];
    const int* rows   = (const int*)d_in[3];
    const int* cols   = (const int*)d_in[4];
    const float* vals = (const float*)d_in[5];
    float* x = (float*)d_out;

    const int n = in_sizes[0] / D;
    const int e = in_sizes[3];
    const int nlayers = in_sizes[1] / (D * D);
    const int npart = (n + ROWS_PER_BLOCK - 1) / ROWS_PER_BLOCK;
    const int ntiles = (n + 31) / 32;
    const size_t e_cap = (size_t)e + 3u * (size_t)n;

    char* ws = (char*)d_ws;
    size_t off = 0;
    auto alloc = [&](size_t bytes) {
        void* p = ws + off;
        off += (bytes + 255) & ~(size_t)255;
        return p;
    };
    unsigned short* m = (unsigned short*)alloc((size_t)n * D * sizeof(unsigned short));
    float* logscale = (float*)alloc((size_t)n * sizeof(float));
    float* xnorm2   = (float*)alloc((size_t)n * sizeof(float));
    int*   counts   = (int*)alloc((size_t)n * sizeof(int));
    int*   row_ptr  = (int*)alloc((size_t)(n + 1) * sizeof(int));
    int*   cursor   = (int*)alloc((size_t)n * sizeof(int));
    int*   partials = (int*)alloc((size_t)(npart > 1024 ? npart : 1024) * sizeof(int));
    float* bhb      = (float*)alloc((size_t)nlayers * D * sizeof(float));
    float* vvb      = (float*)alloc((size_t)nlayers * sizeof(float));
    uint4* whb      = (uint4*)alloc((size_t)nlayers * 2048 * sizeof(uint4));
    uint4* wlb      = (uint4*)alloc((size_t)nlayers * 2048 * sizeof(uint4));
    Edge*  eds      = (Edge*)alloc(e_cap * sizeof(Edge));

    hipMemsetAsync(counts, 0, (size_t)n * sizeof(int), stream);
    hipMemsetAsync(eds, 0, e_cap * sizeof(Edge), stream);
    hist_kernel<<<(e + 255) / 256, 256, 0, stream>>>(rows, counts, e);
    partial_kernel<<<npart, 256, 0, stream>>>(counts, partials, n);
    scan_partials<<<1, 1024, 0, stream>>>(partials, npart);
    rowptr_kernel<<<npart, 256, 0, stream>>>(counts, partials, row_ptr, cursor, n);
    scatter_kernel<<<(e + 255) / 256, 256, 0, stream>>>(rows, cols, vals, cursor, eds, e);

    bias_prep<<<nlayers, 64, 0, stream>>>(bias, bhb, vvb);
    wprep<<<nlayers * 8, 256, 0, stream>>>(W, whb, wlb, nlayers);
    proj_init<<<(n + 15) / 16, 256, 0, stream>>>(ent, x, logscale, xnorm2, n);

    for (int l = 0; l < nlayers; ++l) {
        logmap_gemm<<<ntiles, 256, 0, stream>>>(x, logscale,
                                                whb + (size_t)l * 2048,
                                                wlb + (size_t)l * 2048, m, n);
        int use_act = (l < nlayers - 1) ? 1 : 0;
        aggregate<<<(n + 15) / 16, 256, 0, stream>>>(m, row_ptr, eds, bhb + (size_t)l * D,
                                                     vvb + l, x, logscale, xnorm2, n,
                                                     use_act, (l == nlayers - 1) ? 1 : 0);
    }
}